// Round 4
// baseline (1254.426 us; speedup 1.0000x reference)
//
#include <hip/hip_runtime.h>

#define NB 512
#define NN 256
#define EPG 8192
#define FINC 128

typedef float f32x4 __attribute__((ext_vector_type(4)));

__device__ __forceinline__ float bf2f(unsigned short u) {
  union { unsigned int i; float f; } x; x.i = ((unsigned int)u) << 16; return x.f;
}
__device__ __forceinline__ unsigned short f2bf(float f) {
  union { float f; unsigned int i; } x; x.f = f;
  unsigned int r = x.i + 0x7fffu + ((x.i >> 16) & 1u);
  return (unsigned short)(r >> 16);
}

struct Params {
  const void* x; const void* ei;
  const void *wl1, *bl1, *wr1, *br1, *wro1, *wp, *bp;
  const void *wr2, *br2, *wro2, *wl2, *bl2, *wl3, *bl3;
  float* out; float* ws;
};

// dtype probes (block-uniform); see round-1 notes.
__device__ __forceinline__ bool detect_bf16(const void* p) {
  const unsigned short* pw = (const unsigned short*)p;
  int sane = 0;
  for (int i = 0; i < 64; ++i) {
    unsigned e = (pw[i] >> 7) & 0xFFu;
    sane += (e > 96u && e < 132u) ? 1 : 0;
  }
  return sane >= 56;
}
__device__ __forceinline__ bool detect_i64(const void* p) {
  const int* pi = (const int*)p + EPG;
  int ok = 0;
  for (int i = 0; i < 32; ++i) ok += (pi[i] >= 256 && pi[i] < 512) ? 1 : 0;
  return ok < 24;
}
__device__ __forceinline__ float ldf(const void* p, int i, bool bf) {
  return bf ? bf2f(((const unsigned short*)p)[i]) : ((const float*)p)[i];
}

// ---- dynamic LDS layout (bytes) ----
// X   [0, 66560):       x bf16 rows (stride 260B), dead after P1 ->
//                       tail buffers + conv1/FG weights (offsets below)
// H0  [66560, 103424):  h0 f32 stride 36f (vector rows for scatter reads);
//                       dead after Stage C -> ta f32 stride 21f (21504 B)
// W1/S[103424,123904):  lin1f(16K)+blin1f (P1 only) -> s f32 stride 20f (20480 B)
// AGG [124928,158720):  agg/h1 f32 stride 33f (bank-spread for scatter atomics)
// SC  [158720,160896):  poolf(512f) bpoolf(16f) scr(16f)
#define SMEM_TOTAL 160896

__device__ __forceinline__ float block_sum16(float v, float* scr, int t) {
  #pragma unroll
  for (int o = 32; o > 0; o >>= 1) v += __shfl_xor(v, o, 64);
  __syncthreads();
  if ((t & 63) == 0) scr[t >> 6] = v;
  __syncthreads();
  float s = 0.f;
  #pragma unroll
  for (int i = 0; i < 16; ++i) s += scr[i];
  return s;
}

__global__ __launch_bounds__(1024, 4) void mincut_main(Params P) {
  extern __shared__ char smem[];
  const int t = threadIdx.x;
  const int b = blockIdx.x;

  const bool BF  = detect_bf16(P.wr1);
  const bool I64 = detect_i64(P.ei);

  float* h0buf  = (float*)(smem + 66560);            // stride 36 f
  float* tabuf  = (float*)(smem + 66560);            // after Stage C, stride 21 f
  float* lin1f  = (float*)(smem + 103424);
  float* blin1f = (float*)(smem + 103424 + 16384);
  float* sbuf   = (float*)(smem + 103424);           // s, stride 20 f (post-P1)
  float* aggbuf = (float*)(smem + 124928);           // agg then h1, stride 33 f
  float* poolf  = (float*)(smem + 158720);
  float* bpoolf = (float*)(smem + 158720 + 2048);
  float* scr    = (float*)(smem + 158720 + 2112);    // 16 f
  // X-tail (valid only after P1)
  float* pbuf   = (float*)(smem);            // 512 f
  float* oadjb  = (float*)(smem + 2048);     // 256 f
  float* ssb    = (float*)(smem + 3072);     // 256 f
  float* qbuf   = (float*)(smem + 4096);     // 512 f
  float* ddb    = (float*)(smem + 6144);     // 16 f
  float* h2b    = (float*)(smem + 6208);     // 512 f
  float* rb     = (float*)(smem + 8256);     // 32 f
  float* yb     = (float*)(smem + 8384);     // 32 f
  float* lgb    = (float*)(smem + 8512);     // 12 f
  float* degb   = (float*)(smem + 12288);    // 256 f
  float* ssqb   = (float*)(smem + 13312);    // 256 f
  float* rel2f  = (float*)(smem + 16384);
  float* brel2f = (float*)(smem + 20480);
  float* root2f = (float*)(smem + 20608);
  float* lin2f  = (float*)(smem + 24704);
  float* blin2f = (float*)(smem + 28800);
  float* lin3f  = (float*)(smem + 28928);
  float* blin3f = (float*)(smem + 30208);
  float* rel1f  = (float*)(smem + 32768);    // 1024 f
  float* root1f = (float*)(smem + 36864);    // 1024 f
  float* brel1f = (float*)(smem + 40960);    // 32 f

  const int n4 = t >> 2;      // node for 4-lane-split stages
  const int q4 = t & 3;       // quad slice

  // ---- P0: stage lin1/pool weights (f32) + x (bf16); zero agg ----
  for (int i = t; i < 4096; i += 1024) lin1f[i] = ldf(P.wl1, i, BF);
  if (t < 32) blin1f[t] = ldf(P.bl1, t, BF);
  if (t < 512) poolf[t] = ldf(P.wp, t, BF);
  if (t < 16) bpoolf[t] = ldf(P.bp, t, BF);
  for (int i = t; i < 8448; i += 1024) aggbuf[i] = 0.f;
  if (BF) {
    const unsigned short* gx = (const unsigned short*)P.x + (size_t)b * (NN * FINC);
    #pragma unroll
    for (int it = 0; it < 4; ++it) {
      int g = (it * 1024 + t) * 8;
      int n = g >> 7, k = g & 127;
      uint4 val = *(const uint4*)(gx + g);
      unsigned int* dst = (unsigned int*)(smem + n * 260 + k * 2);
      dst[0] = val.x; dst[1] = val.y; dst[2] = val.z; dst[3] = val.w;
    }
  } else {
    const float* gx = (const float*)P.x + (size_t)b * (NN * FINC);
    #pragma unroll
    for (int it = 0; it < 4; ++it) {
      int g = (it * 1024 + t) * 8;
      int n = g >> 7, k = g & 127;
      float4 v0 = *(const float4*)(gx + g);
      float4 v1 = *(const float4*)(gx + g + 4);
      unsigned int* dst = (unsigned int*)(smem + n * 260 + k * 2);
      dst[0] = (unsigned)f2bf(v0.x) | ((unsigned)f2bf(v0.y) << 16);
      dst[1] = (unsigned)f2bf(v0.z) | ((unsigned)f2bf(v0.w) << 16);
      dst[2] = (unsigned)f2bf(v1.x) | ((unsigned)f2bf(v1.y) << 16);
      dst[3] = (unsigned)f2bf(v1.z) | ((unsigned)f2bf(v1.w) << 16);
    }
  }
  __syncthreads();

  // ---- P1: h0 = x @ W_lin1 + b ; 4 lanes per node, 8 ch each ----
  {
    f32x4 a0 = *(const f32x4*)(blin1f + q4 * 8);
    f32x4 a1 = *(const f32x4*)(blin1f + q4 * 8 + 4);
    const unsigned short* xrow = (const unsigned short*)(smem + n4 * 260);
    const float* wbase = lin1f + q4 * 8;
    for (int k = 0; k < FINC; ++k) {
      float xv = bf2f(xrow[k]);
      const f32x4* wr = (const f32x4*)(wbase + k * 32);
      a0 += xv * wr[0];
      a1 += xv * wr[1];
    }
    float* dst = h0buf + n4 * 36 + q4 * 8;
    *(f32x4*)dst = a0;
    *(f32x4*)(dst + 4) = a1;
  }
  __syncthreads();   // x dead; X-tail usable

  // ---- Phase A: zero deg, stage conv1+FG weights (X-tail), edges -> regs ----
  if (t < 256) degb[t] = 0.f;
  rel1f[t] = ldf(P.wr1, t, BF);
  root1f[t] = ldf(P.wro1, t, BF);
  if (t < 32) brel1f[t] = ldf(P.br1, t, BF);
  rel2f[t] = ldf(P.wr2, t, BF);
  if (t < 32) brel2f[t] = ldf(P.br2, t, BF);
  root2f[t] = ldf(P.wro2, t, BF);
  lin2f[t] = ldf(P.wl2, t, BF);
  if (t < 32) blin2f[t] = ldf(P.bl2, t, BF);
  if (t < 320) lin3f[t] = ldf(P.wl3, t, BF);
  if (t < 10) blin3f[t] = ldf(P.bl3, t, BF);

  int eu[8], ev[8];
  if (I64) {
    const uint4* s4 = (const uint4*)((const long long*)P.ei + (size_t)b * EPG) + t * 4;
    const uint4* d4 = (const uint4*)((const long long*)P.ei + (size_t)NB * EPG + (size_t)b * EPG) + t * 4;
    #pragma unroll
    for (int i = 0; i < 4; ++i) {
      uint4 a = s4[i], c = d4[i];
      eu[2 * i] = a.x & 255; eu[2 * i + 1] = a.z & 255;
      ev[2 * i] = c.x & 255; ev[2 * i + 1] = c.z & 255;
    }
  } else {
    const uint4* s4 = (const uint4*)((const int*)P.ei + (size_t)b * EPG) + t * 2;
    const uint4* d4 = (const uint4*)((const int*)P.ei + (size_t)NB * EPG + (size_t)b * EPG) + t * 2;
    #pragma unroll
    for (int i = 0; i < 2; ++i) {
      uint4 a = s4[i], c = d4[i];
      eu[4 * i] = a.x & 255; eu[4 * i + 1] = a.y & 255; eu[4 * i + 2] = a.z & 255; eu[4 * i + 3] = a.w & 255;
      ev[4 * i] = c.x & 255; ev[4 * i + 1] = c.y & 255; ev[4 * i + 2] = c.z & 255; ev[4 * i + 3] = c.w & 255;
    }
  }
  __syncthreads();

  // ---- P4': sparse scatter  agg[u] += h0[v], deg[u] += 1 ----
  {
    #pragma unroll
    for (int e = 0; e < 8; ++e) {
      const float* hr = h0buf + ev[e] * 36;
      f32x4 h[8];
      #pragma unroll
      for (int j = 0; j < 8; ++j) h[j] = *(const f32x4*)(hr + j * 4);
      float* ar = aggbuf + eu[e] * 33;
      #pragma unroll
      for (int j = 0; j < 8; ++j) {
        #pragma unroll
        for (int c = 0; c < 4; ++c) atomicAdd(ar + j * 4 + c, h[j][c]);
      }
      atomicAdd(degb + eu[e], 1.0f);
    }
  }
  __syncthreads();

  // ---- Stage C: h1 = agg @ W_rel1 + b_rel1 + h0 @ W_root1 ; 4 lanes/node ----
  {
    f32x4 h1a = *(const f32x4*)(brel1f + q4 * 8);
    f32x4 h1b = *(const f32x4*)(brel1f + q4 * 8 + 4);
    const float* arow = aggbuf + n4 * 33;
    const float* hrow = h0buf + n4 * 36;
    const float* wrb = rel1f + q4 * 8;
    const float* wob = root1f + q4 * 8;
    #pragma unroll
    for (int kq = 0; kq < 8; ++kq) {
      f32x4 bv = *(const f32x4*)(hrow + kq * 4);
      #pragma unroll
      for (int j = 0; j < 4; ++j) {
        int k = kq * 4 + j;
        float av = arow[k];
        const f32x4* wr = (const f32x4*)(wrb + k * 32);
        const f32x4* wo = (const f32x4*)(wob + k * 32);
        h1a += av * wr[0] + bv[j] * wo[0];
        h1b += av * wr[1] + bv[j] * wo[1];
      }
    }
    // all reads of row n4 precede these writes in wave-lockstep program order
    float* dsth1 = aggbuf + n4 * 33 + q4 * 8;
    #pragma unroll
    for (int j = 0; j < 4; ++j) { dsth1[j] = h1a[j]; dsth1[4 + j] = h1b[j]; }
  }
  __syncthreads();   // h0 dead; ta region usable

  // ---- Stage D: s = softmax(h1 @ W_pool + b_pool); zero ta ----
  for (int i = t; i < 5376; i += 1024) tabuf[i] = 0.f;
  {
    f32x4 sv = *(const f32x4*)(bpoolf + q4 * 4);
    const float* hrow = aggbuf + n4 * 33;
    const float* wpb = poolf + q4 * 4;
    #pragma unroll 8
    for (int m = 0; m < 32; ++m) sv += hrow[m] * *(const f32x4*)(wpb + m * 16);
    float mx = fmaxf(fmaxf(sv[0], sv[1]), fmaxf(sv[2], sv[3]));
    mx = fmaxf(mx, __shfl_xor(mx, 1, 64));
    mx = fmaxf(mx, __shfl_xor(mx, 2, 64));
    #pragma unroll
    for (int i = 0; i < 4; ++i) sv[i] = __expf(sv[i] - mx);
    float sm = sv[0] + sv[1] + sv[2] + sv[3];
    sm += __shfl_xor(sm, 1, 64);
    sm += __shfl_xor(sm, 2, 64);
    float inv = 1.f / sm;
    #pragma unroll
    for (int i = 0; i < 4; ++i) sv[i] *= inv;
    float sq = sv[0] * sv[0] + sv[1] * sv[1] + sv[2] * sv[2] + sv[3] * sv[3];
    sq += __shfl_xor(sq, 1, 64);
    sq += __shfl_xor(sq, 2, 64);
    if (q4 == 0) ssqb[n4] = sq;
    *(f32x4*)(sbuf + n4 * 20 + q4 * 4) = sv;
  }
  __syncthreads();

  // ---- P5': sparse scatter  ta[u] += s[v] ----
  {
    #pragma unroll
    for (int e = 0; e < 8; ++e) {
      const float* sr = sbuf + ev[e] * 20;
      f32x4 s0 = *(const f32x4*)(sr);
      f32x4 s1 = *(const f32x4*)(sr + 4);
      f32x4 s2 = *(const f32x4*)(sr + 8);
      f32x4 s3 = *(const f32x4*)(sr + 12);
      float* tr = tabuf + eu[e] * 21;
      #pragma unroll
      for (int c = 0; c < 4; ++c) {
        atomicAdd(tr + c, s0[c]);
        atomicAdd(tr + 4 + c, s1[c]);
        atomicAdd(tr + 8 + c, s2[c]);
        atomicAdd(tr + 12 + c, s3[c]);
      }
    }
  }
  __syncthreads();

  // ---- P6: fused rank-256 reductions ----
  if (t < 512) {
    const int kp = t >> 5, cp = t & 31;
    float pa = 0.f;
    for (int n = 0; n < 256; ++n) pa += sbuf[n * 20 + kp] * aggbuf[n * 33 + cp];
    pbuf[kp * 32 + cp] = pa;
  } else if (t < 768) {
    const int i = t - 512, k3 = i >> 4, j3 = i & 15;
    float oa = 0.f;
    for (int n = 0; n < 256; ++n) oa += sbuf[n * 20 + k3] * tabuf[n * 21 + j3];
    oadjb[i] = oa;
  } else {
    const int i = t - 768, k3 = i >> 4, j3 = i & 15;
    float sa = 0.f;
    for (int n = 0; n < 256; ++n) sa += sbuf[n * 20 + k3] * sbuf[n * 20 + j3];
    ssb[i] = sa;
  }
  __syncthreads();

  // ---- losses ----
  {
    float den = block_sum16((t < 256) ? degb[t] * ssqb[t] : 0.f, scr, t);
    float num = block_sum16((t < 16) ? oadjb[t * 17] : 0.f, scr, t);
    float fro = block_sum16((t < 256) ? ssb[t] * ssb[t] : 0.f, scr, t);
    float ssn = sqrtf(fro);
    float term = 0.f;
    if (t < 256) {
      float diag = ((t & 15) == (t >> 4)) ? 0.25f : 0.f;
      term = ssb[t] / ssn - diag;
    }
    float orth = block_sum16(term * term, scr, t);
    if (t == 0) {
      atomicAdd(P.ws, -(num / den) * (1.f / NB));
      atomicAdd(P.ws + 1, sqrtf(orth) * (1.f / NB));
    }
  }
  __syncthreads();

  // ---- P7: normalize pooled adjacency ----
  if (t < 16) {
    float rs = 0.f;
    #pragma unroll
    for (int j = 0; j < 16; ++j) if (j != t) rs += oadjb[t * 16 + j];
    ddb[t] = sqrtf(rs) + 1e-15f;
  }
  __syncthreads();
  if (t < 256) {
    int k = t >> 4, j = t & 15;
    float apv = (k == j) ? 0.f : oadjb[t] / (ddb[k] * ddb[j]);
    oadjb[t] = apv;
  }
  __syncthreads();

  // ---- conv2 + readout + MLP + log_softmax ----
  if (t < 512) {
    int k = t >> 5, c = t & 31;
    float q = 0.f;
    #pragma unroll
    for (int j = 0; j < 16; ++j) q += oadjb[k * 16 + j] * pbuf[j * 32 + c];
    qbuf[k * 32 + c] = q;
  }
  __syncthreads();
  if (t < 512) {
    int k = t >> 5, c = t & 31;
    float a1 = brel2f[c];
    #pragma unroll
    for (int m = 0; m < 32; ++m)
      a1 += qbuf[k * 32 + m] * rel2f[m * 32 + c] + pbuf[k * 32 + m] * root2f[m * 32 + c];
    h2b[k * 32 + c] = a1;
  }
  __syncthreads();
  if (t < 32) {
    float r = 0.f;
    #pragma unroll
    for (int k = 0; k < 16; ++k) r += h2b[k * 32 + t];
    rb[t] = r;
  }
  __syncthreads();
  if (t < 32) {
    float y = blin2f[t];
    #pragma unroll
    for (int m = 0; m < 32; ++m) y += rb[m] * lin2f[m * 32 + t];
    yb[t] = fmaxf(y, 0.f);
  }
  __syncthreads();
  if (t < 10) {
    float lg = blin3f[t];
    #pragma unroll
    for (int m = 0; m < 32; ++m) lg += yb[m] * lin3f[m * 10 + t];
    lgb[t] = lg;
  }
  __syncthreads();
  if (t == 0) {
    float mx = lgb[0];
    #pragma unroll
    for (int i = 1; i < 10; ++i) mx = fmaxf(mx, lgb[i]);
    float sum = 0.f;
    #pragma unroll
    for (int i = 0; i < 10; ++i) sum += __expf(lgb[i] - mx);
    lgb[10] = mx + __logf(sum);
  }
  __syncthreads();
  if (t < 10) {
    float val = lgb[t] - lgb[10];
    if (BF) ((unsigned short*)P.out)[b * 10 + t] = f2bf(val);
    else    P.out[b * 10 + t] = val;
  }
}

__global__ void mincut_fin(Params P) {
  if (threadIdx.x == 0) {
    const bool BF = detect_bf16(P.wr1);
    if (BF) {
      ((unsigned short*)P.out)[5120] = f2bf(P.ws[0]);
      ((unsigned short*)P.out)[5121] = f2bf(P.ws[1]);
    } else {
      P.out[5120] = P.ws[0];
      P.out[5121] = P.ws[1];
    }
  }
}

extern "C" void kernel_launch(void* const* d_in, const int* in_sizes, int n_in,
                              void* d_out, int out_size, void* d_ws, size_t ws_size,
                              hipStream_t stream) {
  (void)in_sizes; (void)n_in; (void)out_size; (void)ws_size;
  Params P;
  P.x    = d_in[0];
  P.ei   = d_in[1];
  P.wl1  = d_in[3];
  P.bl1  = d_in[4];
  P.wr1  = d_in[5];
  P.br1  = d_in[6];
  P.wro1 = d_in[7];
  P.wp   = d_in[8];
  P.bp   = d_in[9];
  P.wr2  = d_in[10];
  P.br2  = d_in[11];
  P.wro2 = d_in[12];
  P.wl2  = d_in[13];
  P.bl2  = d_in[14];
  P.wl3  = d_in[15];
  P.bl3  = d_in[16];
  P.out  = (float*)d_out;
  P.ws   = (float*)d_ws;

  hipMemsetAsync(d_ws, 0, 2 * sizeof(float), stream);
  hipFuncSetAttribute(reinterpret_cast<const void*>(mincut_main),
                      hipFuncAttributeMaxDynamicSharedMemorySize, SMEM_TOTAL);
  hipLaunchKernelGGL(mincut_main, dim3(NB), dim3(1024), SMEM_TOTAL, stream, P);
  hipLaunchKernelGGL(mincut_fin, dim3(1), dim3(64), 0, stream, P);
}

// Round 5
// 211.507 us; speedup vs baseline: 5.9309x; 5.9309x over previous
//
#include <hip/hip_runtime.h>

#define NB 512
#define NN 256
#define EPG 8192
#define FINC 128

typedef float f32x4 __attribute__((ext_vector_type(4)));
typedef short s16x8 __attribute__((ext_vector_type(8)));

__device__ __forceinline__ float bf2f(unsigned short u) {
  union { unsigned int i; float f; } x; x.i = ((unsigned int)u) << 16; return x.f;
}
__device__ __forceinline__ unsigned short f2bf(float f) {
  union { float f; unsigned int i; } x; x.f = f;
  unsigned int r = x.i + 0x7fffu + ((x.i >> 16) & 1u);
  return (unsigned short)(r >> 16);
}
// exact for small non-negative integers (counts <= 255)
__device__ __forceinline__ short ftrunc_bf(float f) {
  union { float f; unsigned int i; } x; x.f = f;
  return (short)(x.i >> 16);
}

struct Params {
  const void* x; const void* ei;
  const void *wl1, *bl1, *wr1, *br1, *wro1, *wp, *bp;
  const void *wr2, *br2, *wro2, *wl2, *bl2, *wl3, *bl3;
  float* out; float* ws;
};

// dtype probes (block-uniform); see round-1 notes.
__device__ __forceinline__ bool detect_bf16(const void* p) {
  const unsigned short* pw = (const unsigned short*)p;
  int sane = 0;
  for (int i = 0; i < 64; ++i) {
    unsigned e = (pw[i] >> 7) & 0xFFu;
    sane += (e > 96u && e < 132u) ? 1 : 0;
  }
  return sane >= 56;
}
__device__ __forceinline__ bool detect_i64(const void* p) {
  const int* pi = (const int*)p + EPG;
  int ok = 0;
  for (int i = 0; i < 32; ++i) ok += (pi[i] >= 256 && pi[i] < 512) ? 1 : 0;
  return ok < 24;
}
__device__ __forceinline__ float ldf(const void* p, int i, bool bf) {
  return bf ? bf2f(((const unsigned short*)p)[i]) : ((const float*)p)[i];
}

// ---- dynamic LDS layout (bytes) ----
// R0 [0, 66560):       adj u8 row-major [u][v] stride 260 (built P2/P3, dead
//                      after P5) -> tail buffers + FG weights (P6 on)
// R1 [66560, 103424):  h0 f32 stride 36 (P1->StageC); then tabuf f32 stride 17
//                      [0,17408) + sT bf16 hi/lo [16][264] x2 [17408,34304)
// R2 [103424,140288):  W1T bf16 hi/lo [32][136] x2 (P0->P1); then agg/h1 f32
//                      stride 36 (P4->P6)
// R3 [140288,160768):  h0T bf16 [32][264] (P1->P4); then conv1 weights f32
//                      (StageC); then s f32 stride 20 (StageD->P6)
// R4 [160768,163072):  poolh bf16(1024B) bpoolf(64) blin1f(128) scr(64) degb(1024)
#define SMEM_TOTAL 163072

__device__ __forceinline__ float block_sum16(float v, float* scr, int t) {
  #pragma unroll
  for (int o = 32; o > 0; o >>= 1) v += __shfl_xor(v, o, 64);
  __syncthreads();
  if ((t & 63) == 0) scr[t >> 6] = v;
  __syncthreads();
  float s = 0.f;
  #pragma unroll
  for (int i = 0; i < 16; ++i) s += scr[i];
  return s;
}

__global__ __launch_bounds__(1024, 4) void mincut_main(Params P) {
  extern __shared__ char smem[];
  const int t = threadIdx.x;
  const int b = blockIdx.x;

  const bool BF  = detect_bf16(P.wr1);
  const bool I64 = detect_i64(P.ei);

  float* h0buf  = (float*)(smem + 66560);                    // stride 36
  float* tabuf  = (float*)(smem + 66560);                    // stride 17 (post-StageC)
  unsigned short* sTh = (unsigned short*)(smem + 66560 + 17408);   // [16][264]
  unsigned short* sTl = (unsigned short*)(smem + 66560 + 25856);   // [16][264]
  float* aggbuf = (float*)(smem + 103424);                   // stride 36
  unsigned short* w1th = (unsigned short*)(smem + 103424);         // [32][136]
  unsigned short* w1tl = (unsigned short*)(smem + 103424 + 8704);  // [32][136]
  unsigned short* h0T  = (unsigned short*)(smem + 140288);         // [32][264]
  float* rel1f  = (float*)(smem + 140288);
  float* root1f = (float*)(smem + 140288 + 4096);
  float* brel1f = (float*)(smem + 140288 + 8192);
  float* sbuf   = (float*)(smem + 140288);                   // stride 20 (StageD on)
  unsigned short* poolh = (unsigned short*)(smem + 160768);  // 512 bf16
  float* bpoolf = (float*)(smem + 160768 + 1024);            // 16 f
  float* blin1f = (float*)(smem + 160768 + 1088);            // 32 f
  float* scr    = (float*)(smem + 160768 + 1216);            // 16 f
  float* degb   = (float*)(smem + 160768 + 1280);            // 256 f
  // R0 tail (valid from P6)
  float* pbuf   = (float*)(smem);            // 512 f
  float* oadjb  = (float*)(smem + 2048);     // 256 f
  float* ssb    = (float*)(smem + 3072);     // 256 f
  float* qbuf   = (float*)(smem + 4096);     // 512 f
  float* ddb    = (float*)(smem + 6144);     // 16 f
  float* h2b    = (float*)(smem + 6208);     // 512 f
  float* rb     = (float*)(smem + 8256);     // 32 f
  float* yb     = (float*)(smem + 8384);     // 32 f
  float* lgb    = (float*)(smem + 8512);     // 12 f
  float* rel2f  = (float*)(smem + 16384);
  float* brel2f = (float*)(smem + 20480);
  float* root2f = (float*)(smem + 20608);
  float* lin2f  = (float*)(smem + 24704);
  float* blin2f = (float*)(smem + 28800);
  float* lin3f  = (float*)(smem + 28928);
  float* blin3f = (float*)(smem + 30208);

  const int n4 = t >> 2, q4 = t & 3;            // VALU stages
  const int wv = t >> 6, lane = t & 63;         // MFMA stages
  const int lm = lane & 15, quad = lane >> 4;
  const int mbase = wv * 16;

  // ---- P0: stage W1T bf16 hi/lo, biases, pool weights ----
  for (int e = t; e < 4096; e += 1024) {
    int k = e >> 5, c = e & 31;
    float w = ldf(P.wl1, e, BF);
    unsigned short hi = f2bf(w);
    w1th[c * 136 + k] = hi;
    w1tl[c * 136 + k] = f2bf(w - bf2f(hi));
  }
  if (t < 32) blin1f[t] = ldf(P.bl1, t, BF);
  if (t < 512) poolh[t] = f2bf(ldf(P.wp, t, BF));
  if (t < 16) bpoolf[t] = ldf(P.bp, t, BF);
  __syncthreads();

  // ---- P1: h0 = x @ W1 + b (MFMA; x from global, W hi/lo) ----
  {
    f32x4 acc[2] = {{0.f,0.f,0.f,0.f},{0.f,0.f,0.f,0.f}};
    const size_t node = (size_t)(b * 256 + mbase + lm);
    #pragma unroll
    for (int ks = 0; ks < 4; ++ks) {
      const int k0 = ks * 32 + quad * 8;
      s16x8 a;
      if (BF) {
        a = *(const s16x8*)((const unsigned short*)P.x + node * 128 + k0);
      } else {
        const float* xp = (const float*)P.x + node * 128 + k0;
        f32x4 v0 = *(const f32x4*)xp;
        f32x4 v1 = *(const f32x4*)(xp + 4);
        #pragma unroll
        for (int j = 0; j < 4; ++j) { a[j] = (short)f2bf(v0[j]); a[4 + j] = (short)f2bf(v1[j]); }
      }
      #pragma unroll
      for (int ct = 0; ct < 2; ++ct) {
        const int c = ct * 16 + lm;
        s16x8 bh = *(const s16x8*)(w1th + c * 136 + k0);
        s16x8 bl = *(const s16x8*)(w1tl + c * 136 + k0);
        acc[ct] = __builtin_amdgcn_mfma_f32_16x16x32_bf16(a, bh, acc[ct], 0, 0, 0);
        acc[ct] = __builtin_amdgcn_mfma_f32_16x16x32_bf16(a, bl, acc[ct], 0, 0, 0);
      }
    }
    #pragma unroll
    for (int ct = 0; ct < 2; ++ct) {
      const int c = ct * 16 + lm;
      float bias = blin1f[c];
      #pragma unroll
      for (int r = 0; r < 4; ++r) {
        int row = mbase + quad * 4 + r;
        float val = acc[ct][r] + bias;
        h0buf[row * 36 + c] = val;
        h0T[c * 264 + row] = f2bf(val);
      }
    }
  }
  __syncthreads();

  // ---- P2: zero adjacency region ----
  {
    uint4 z = {0u, 0u, 0u, 0u};
    for (int i = t; i < 4160; i += 1024) ((uint4*)smem)[i] = z;
  }
  __syncthreads();

  // ---- P3: build u8 adjacency ROW-major [u=src][v=dst], packed-byte atomics ----
  if (I64) {
    const long long* es = (const long long*)P.ei + (size_t)b * EPG;
    const long long* ed = (const long long*)P.ei + (size_t)NB * EPG + (size_t)b * EPG;
    #pragma unroll
    for (int i2 = 0; i2 < 8; ++i2) {
      int e = i2 * 1024 + t;
      unsigned idx = (unsigned)((((int)es[e]) & 255) * 260 + (((int)ed[e]) & 255));
      atomicAdd((unsigned int*)(smem + (idx & ~3u)), 1u << ((idx & 3u) * 8u));
    }
  } else {
    const int* es = (const int*)P.ei + (size_t)b * EPG;
    const int* ed = (const int*)P.ei + (size_t)NB * EPG + (size_t)b * EPG;
    #pragma unroll
    for (int i2 = 0; i2 < 8; ++i2) {
      int e = i2 * 1024 + t;
      unsigned idx = (unsigned)((es[e] & 255) * 260 + (ed[e] & 255));
      atomicAdd((unsigned int*)(smem + (idx & ~3u)), 1u << ((idx & 3u) * 8u));
    }
  }
  __syncthreads();

  // ---- P4: agg = A @ h0 (MFMA, A-frags cached; deg via shuffles) ----
  s16x8 afr[8];
  {
    f32x4 acc[2] = {{0.f,0.f,0.f,0.f},{0.f,0.f,0.f,0.f}};
    float dsum = 0.f;
    #pragma unroll
    for (int ks = 0; ks < 8; ++ks) {
      const int v0 = ks * 32 + quad * 8;
      const char* ap = smem + (mbase + lm) * 260 + v0;
      unsigned d0 = *(const unsigned int*)(ap);
      unsigned d1 = *(const unsigned int*)(ap + 4);
      s16x8 a;
      #pragma unroll
      for (int j = 0; j < 4; ++j) {
        float f0 = (float)((d0 >> (8 * j)) & 255u);
        float f1 = (float)((d1 >> (8 * j)) & 255u);
        dsum += f0 + f1;
        a[j] = ftrunc_bf(f0);
        a[4 + j] = ftrunc_bf(f1);
      }
      afr[ks] = a;
      #pragma unroll
      for (int ct = 0; ct < 2; ++ct) {
        s16x8 bf = *(const s16x8*)(h0T + (ct * 16 + lm) * 264 + v0);
        acc[ct] = __builtin_amdgcn_mfma_f32_16x16x32_bf16(a, bf, acc[ct], 0, 0, 0);
      }
    }
    #pragma unroll
    for (int ct = 0; ct < 2; ++ct) {
      const int c = ct * 16 + lm;
      #pragma unroll
      for (int r = 0; r < 4; ++r) aggbuf[(mbase + quad * 4 + r) * 36 + c] = acc[ct][r];
    }
    dsum += __shfl_xor(dsum, 16, 64);
    dsum += __shfl_xor(dsum, 32, 64);
    if (lane < 16) degb[mbase + lm] = dsum;
  }
  __syncthreads();

  // ---- stage conv1 weights (over dead h0T) ----
  rel1f[t] = ldf(P.wr1, t, BF);
  root1f[t] = ldf(P.wro1, t, BF);
  if (t < 32) brel1f[t] = ldf(P.br1, t, BF);
  __syncthreads();

  // ---- Stage C: h1 = agg @ W_rel1 + b_rel1 + h0 @ W_root1 (VALU, 4 lanes/node) ----
  {
    f32x4 h1a = *(const f32x4*)(brel1f + q4 * 8);
    f32x4 h1b = *(const f32x4*)(brel1f + q4 * 8 + 4);
    const float* arow = aggbuf + n4 * 36;
    const float* hrow = h0buf + n4 * 36;
    const float* wrb = rel1f + q4 * 8;
    const float* wob = root1f + q4 * 8;
    #pragma unroll
    for (int kq = 0; kq < 8; ++kq) {
      f32x4 av = *(const f32x4*)(arow + kq * 4);
      f32x4 bv = *(const f32x4*)(hrow + kq * 4);
      #pragma unroll
      for (int j = 0; j < 4; ++j) {
        int k = kq * 4 + j;
        const f32x4* wr = (const f32x4*)(wrb + k * 32);
        const f32x4* wo = (const f32x4*)(wob + k * 32);
        h1a += av[j] * wr[0] + bv[j] * wo[0];
        h1b += av[j] * wr[1] + bv[j] * wo[1];
      }
    }
    float* dsth1 = aggbuf + n4 * 36 + q4 * 8;  // row reads precede writes in wave lockstep
    *(f32x4*)dsth1 = h1a;
    *(f32x4*)(dsth1 + 4) = h1b;
  }
  __syncthreads();   // h0f32 + conv1 weights dead

  // ---- Stage D: s = softmax(h1 @ W_pool + b); write s f32 + sT bf16 hi/lo ----
  float ssq;
  {
    f32x4 sv = *(const f32x4*)(bpoolf + q4 * 4);
    const float* hrow = aggbuf + n4 * 36;
    #pragma unroll 8
    for (int m = 0; m < 32; ++m) {
      float hm = hrow[m];
      uint2 pw = *(const uint2*)(poolh + m * 16 + q4 * 4);
      sv[0] += hm * bf2f((unsigned short)(pw.x & 0xFFFFu));
      sv[1] += hm * bf2f((unsigned short)(pw.x >> 16));
      sv[2] += hm * bf2f((unsigned short)(pw.y & 0xFFFFu));
      sv[3] += hm * bf2f((unsigned short)(pw.y >> 16));
    }
    float mx = fmaxf(fmaxf(sv[0], sv[1]), fmaxf(sv[2], sv[3]));
    mx = fmaxf(mx, __shfl_xor(mx, 1, 64));
    mx = fmaxf(mx, __shfl_xor(mx, 2, 64));
    #pragma unroll
    for (int i = 0; i < 4; ++i) sv[i] = __expf(sv[i] - mx);
    float sm = sv[0] + sv[1] + sv[2] + sv[3];
    sm += __shfl_xor(sm, 1, 64);
    sm += __shfl_xor(sm, 2, 64);
    float inv = 1.f / sm;
    #pragma unroll
    for (int i = 0; i < 4; ++i) sv[i] *= inv;
    float sq = sv[0] * sv[0] + sv[1] * sv[1] + sv[2] * sv[2] + sv[3] * sv[3];
    sq += __shfl_xor(sq, 1, 64);
    sq += __shfl_xor(sq, 2, 64);
    ssq = sq;
    *(f32x4*)(sbuf + n4 * 20 + q4 * 4) = sv;
    #pragma unroll
    for (int i = 0; i < 4; ++i) {
      int cl = q4 * 4 + i;
      unsigned short hi = f2bf(sv[i]);
      sTh[cl * 264 + n4] = hi;
      sTl[cl * 264 + n4] = f2bf(sv[i] - bf2f(hi));
    }
  }
  __syncthreads();

  // ---- P5: tA = A @ s (MFMA, cached A-frags, s hi/lo) ----
  {
    f32x4 tacc = {0.f, 0.f, 0.f, 0.f};
    #pragma unroll
    for (int ks = 0; ks < 8; ++ks) {
      const int v0 = ks * 32 + quad * 8;
      s16x8 bh = *(const s16x8*)(sTh + lm * 264 + v0);
      s16x8 bl = *(const s16x8*)(sTl + lm * 264 + v0);
      tacc = __builtin_amdgcn_mfma_f32_16x16x32_bf16(afr[ks], bh, tacc, 0, 0, 0);
      tacc = __builtin_amdgcn_mfma_f32_16x16x32_bf16(afr[ks], bl, tacc, 0, 0, 0);
    }
    #pragma unroll
    for (int r = 0; r < 4; ++r) tabuf[(mbase + quad * 4 + r) * 17 + lm] = tacc[r];
  }
  __syncthreads();   // adjacency dead from here

  // ---- P6: FG weights into R0 tail + fused rank-256 reductions ----
  rel2f[t] = ldf(P.wr2, t, BF);
  if (t < 32) brel2f[t] = ldf(P.br2, t, BF);
  root2f[t] = ldf(P.wro2, t, BF);
  lin2f[t] = ldf(P.wl2, t, BF);
  if (t < 32) blin2f[t] = ldf(P.bl2, t, BF);
  if (t < 320) lin3f[t] = ldf(P.wl3, t, BF);
  if (t < 10) blin3f[t] = ldf(P.bl3, t, BF);

  if (t < 512) {
    const int kp = t >> 5, cp = t & 31;
    float pa = 0.f;
    for (int n = 0; n < 256; ++n) pa += sbuf[n * 20 + kp] * aggbuf[n * 36 + cp];
    pbuf[kp * 32 + cp] = pa;
  } else if (t < 768) {
    const int i = t - 512, k3 = i >> 4, j3 = i & 15;
    float oa = 0.f;
    for (int n = 0; n < 256; ++n) oa += sbuf[n * 20 + k3] * tabuf[n * 17 + j3];
    oadjb[i] = oa;
  } else {
    const int i = t - 768, k3 = i >> 4, j3 = i & 15;
    float sa = 0.f;
    for (int n = 0; n < 256; ++n) sa += sbuf[n * 20 + k3] * sbuf[n * 20 + j3];
    ssb[i] = sa;
  }
  __syncthreads();

  // ---- losses ----
  {
    float den = block_sum16((q4 == 0) ? degb[n4] * ssq : 0.f, scr, t);
    float num = block_sum16((t < 16) ? oadjb[t * 17] : 0.f, scr, t);
    float fro = block_sum16((t < 256) ? ssb[t] * ssb[t] : 0.f, scr, t);
    float ssn = sqrtf(fro);
    float term = 0.f;
    if (t < 256) {
      float diag = ((t & 15) == (t >> 4)) ? 0.25f : 0.f;
      term = ssb[t] / ssn - diag;
    }
    float orth = block_sum16(term * term, scr, t);
    if (t == 0) {
      atomicAdd(P.ws, -(num / den) * (1.f / NB));
      atomicAdd(P.ws + 1, sqrtf(orth) * (1.f / NB));
    }
  }
  __syncthreads();

  // ---- P7: normalize pooled adjacency ----
  if (t < 16) {
    float rs = 0.f;
    #pragma unroll
    for (int j = 0; j < 16; ++j) if (j != t) rs += oadjb[t * 16 + j];
    ddb[t] = sqrtf(rs) + 1e-15f;
  }
  __syncthreads();
  if (t < 256) {
    int k = t >> 4, j = t & 15;
    float apv = (k == j) ? 0.f : oadjb[t] / (ddb[k] * ddb[j]);
    oadjb[t] = apv;
  }
  __syncthreads();

  // ---- conv2 + readout + MLP + log_softmax ----
  if (t < 512) {
    int k = t >> 5, c = t & 31;
    float q = 0.f;
    #pragma unroll
    for (int j = 0; j < 16; ++j) q += oadjb[k * 16 + j] * pbuf[j * 32 + c];
    qbuf[k * 32 + c] = q;
  }
  __syncthreads();
  if (t < 512) {
    int k = t >> 5, c = t & 31;
    float a1 = brel2f[c];
    #pragma unroll
    for (int m = 0; m < 32; ++m)
      a1 += qbuf[k * 32 + m] * rel2f[m * 32 + c] + pbuf[k * 32 + m] * root2f[m * 32 + c];
    h2b[k * 32 + c] = a1;
  }
  __syncthreads();
  if (t < 32) {
    float r = 0.f;
    #pragma unroll
    for (int k = 0; k < 16; ++k) r += h2b[k * 32 + t];
    rb[t] = r;
  }
  __syncthreads();
  if (t < 32) {
    float y = blin2f[t];
    #pragma unroll
    for (int m = 0; m < 32; ++m) y += rb[m] * lin2f[m * 32 + t];
    yb[t] = fmaxf(y, 0.f);
  }
  __syncthreads();
  if (t < 10) {
    float lg = blin3f[t];
    #pragma unroll
    for (int m = 0; m < 32; ++m) lg += yb[m] * lin3f[m * 10 + t];
    lgb[t] = lg;
  }
  __syncthreads();
  if (t == 0) {
    float mx = lgb[0];
    #pragma unroll
    for (int i = 1; i < 10; ++i) mx = fmaxf(mx, lgb[i]);
    float sum = 0.f;
    #pragma unroll
    for (int i = 0; i < 10; ++i) sum += __expf(lgb[i] - mx);
    lgb[10] = mx + __logf(sum);
  }
  __syncthreads();
  if (t < 10) {
    float val = lgb[t] - lgb[10];
    if (BF) ((unsigned short*)P.out)[b * 10 + t] = f2bf(val);
    else    P.out[b * 10 + t] = val;
  }
}

__global__ void mincut_fin(Params P) {
  if (threadIdx.x == 0) {
    const bool BF = detect_bf16(P.wr1);
    if (BF) {
      ((unsigned short*)P.out)[5120] = f2bf(P.ws[0]);
      ((unsigned short*)P.out)[5121] = f2bf(P.ws[1]);
    } else {
      P.out[5120] = P.ws[0];
      P.out[5121] = P.ws[1];
    }
  }
}

extern "C" void kernel_launch(void* const* d_in, const int* in_sizes, int n_in,
                              void* d_out, int out_size, void* d_ws, size_t ws_size,
                              hipStream_t stream) {
  (void)in_sizes; (void)n_in; (void)out_size; (void)ws_size;
  Params P;
  P.x    = d_in[0];
  P.ei   = d_in[1];
  P.wl1  = d_in[3];
  P.bl1  = d_in[4];
  P.wr1  = d_in[5];
  P.br1  = d_in[6];
  P.wro1 = d_in[7];
  P.wp   = d_in[8];
  P.bp   = d_in[9];
  P.wr2  = d_in[10];
  P.br2  = d_in[11];
  P.wro2 = d_in[12];
  P.wl2  = d_in[13];
  P.bl2  = d_in[14];
  P.wl3  = d_in[15];
  P.bl3  = d_in[16];
  P.out  = (float*)d_out;
  P.ws   = (float*)d_ws;

  hipMemsetAsync(d_ws, 0, 2 * sizeof(float), stream);
  hipFuncSetAttribute(reinterpret_cast<const void*>(mincut_main),
                      hipFuncAttributeMaxDynamicSharedMemorySize, SMEM_TOTAL);
  hipLaunchKernelGGL(mincut_main, dim3(NB), dim3(1024), SMEM_TOTAL, stream, P);
  hipLaunchKernelGGL(mincut_fin, dim3(1), dim3(64), 0, stream, P);
}

// Round 6
// 196.542 us; speedup vs baseline: 6.3825x; 1.0761x over previous
//
#include <hip/hip_runtime.h>

#define NB 512
#define NN 256
#define EPG 8192
#define FINC 128

typedef float f32x4 __attribute__((ext_vector_type(4)));
typedef short s16x8 __attribute__((ext_vector_type(8)));

__device__ __forceinline__ float bf2f(unsigned short u) {
  union { unsigned int i; float f; } x; x.i = ((unsigned int)u) << 16; return x.f;
}
__device__ __forceinline__ unsigned short f2bf(float f) {
  union { float f; unsigned int i; } x; x.f = f;
  unsigned int r = x.i + 0x7fffu + ((x.i >> 16) & 1u);
  return (unsigned short)(r >> 16);
}
// exact for small non-negative integers (counts <= 255)
__device__ __forceinline__ short ftrunc_bf(float f) {
  union { float f; unsigned int i; } x; x.f = f;
  return (short)(x.i >> 16);
}

struct Params {
  const void* x; const void* ei;
  const void *wl1, *bl1, *wr1, *br1, *wro1, *wp, *bp;
  const void *wr2, *br2, *wro2, *wl2, *bl2, *wl3, *bl3;
  float* out; float* ws;
};

// dtype probes (block-uniform); see round-1 notes.
__device__ __forceinline__ bool detect_bf16(const void* p) {
  const unsigned short* pw = (const unsigned short*)p;
  int sane = 0;
  for (int i = 0; i < 64; ++i) {
    unsigned e = (pw[i] >> 7) & 0xFFu;
    sane += (e > 96u && e < 132u) ? 1 : 0;
  }
  return sane >= 56;
}
__device__ __forceinline__ bool detect_i64(const void* p) {
  const int* pi = (const int*)p + EPG;
  int ok = 0;
  for (int i = 0; i < 32; ++i) ok += (pi[i] >= 256 && pi[i] < 512) ? 1 : 0;
  return ok < 24;
}
__device__ __forceinline__ float ldf(const void* p, int i, bool bf) {
  return bf ? bf2f(((const unsigned short*)p)[i]) : ((const float*)p)[i];
}

// ---- dynamic LDS layout (bytes) ----
// R0 [0, 66560):       adj u8 row-major [u][v] stride 260 (P2..P5) ->
//                      P6 on: final small bufs [0,8524), FG weights
//                      [16384,30336), MFMA job outputs [40960,50176)
// R1 [66560, 103424):  h0 f32 stride 36 (P1->StageC); then taT bf16 [16][264]
//                      @66560, sTh @75008, sTl @83456 (each [16][264])
// R2 [103424,140288):  W1T bf16 hi/lo [32][136] (P0->P1); then agg f32
//                      stride 36 (P4->StageC), then h1 f32 stride 36 (->StageD)
// R3 [140288,160768):  h0T bf16 [32][264] (P1->P4); then wrelTh/l + wrootTh
//                      [32][40] (StageC); then h1Th bf16 [32][264] (->P6)
// R4 [160768,163072):  poolh(1024B) bpoolf(64) blin1f(128) scr(64) degb(1024)
#define SMEM_TOTAL 163072

__device__ __forceinline__ float block_sum16(float v, float* scr, int t) {
  #pragma unroll
  for (int o = 32; o > 0; o >>= 1) v += __shfl_xor(v, o, 64);
  __syncthreads();
  if ((t & 63) == 0) scr[t >> 6] = v;
  __syncthreads();
  float s = 0.f;
  #pragma unroll
  for (int i = 0; i < 16; ++i) s += scr[i];
  return s;
}

__global__ __launch_bounds__(1024, 4) void mincut_main(Params P) {
  extern __shared__ char smem[];
  const int t = threadIdx.x;
  const int b = blockIdx.x;

  const bool BF  = detect_bf16(P.wr1);
  const bool I64 = detect_i64(P.ei);

  float* h0buf  = (float*)(smem + 66560);                    // stride 36
  unsigned short* taT = (unsigned short*)(smem + 66560);           // [16][264]
  unsigned short* sTh = (unsigned short*)(smem + 66560 + 8448);    // [16][264]
  unsigned short* sTl = (unsigned short*)(smem + 66560 + 16896);   // [16][264]
  float* aggbuf = (float*)(smem + 103424);                   // agg then h1, stride 36
  unsigned short* w1th = (unsigned short*)(smem + 103424);         // [32][136]
  unsigned short* w1tl = (unsigned short*)(smem + 103424 + 8704);  // [32][136]
  unsigned short* h0T  = (unsigned short*)(smem + 140288);         // [32][264]
  unsigned short* wrelTh  = (unsigned short*)(smem + 140288);      // [32][40]
  unsigned short* wrelTl  = (unsigned short*)(smem + 140288 + 2560);
  unsigned short* wrootTh = (unsigned short*)(smem + 140288 + 5120);
  float* brel1f = (float*)(smem + 140288 + 7680);            // 32 f
  unsigned short* h1Th = (unsigned short*)(smem + 140288);         // [32][264] (post-StageC)
  unsigned short* poolh = (unsigned short*)(smem + 160768);  // 512 bf16
  float* bpoolf = (float*)(smem + 160768 + 1024);            // 16 f
  float* blin1f = (float*)(smem + 160768 + 1088);            // 32 f
  float* scr    = (float*)(smem + 160768 + 1216);            // 16 f
  float* degb   = (float*)(smem + 160768 + 1280);            // 256 f
  // R0 tail (valid from P6)
  float* pbuf   = (float*)(smem);            // 512 f
  float* oadjb  = (float*)(smem + 2048);     // 256 f
  float* ssb    = (float*)(smem + 3072);     // 256 f
  float* qbuf   = (float*)(smem + 4096);     // 512 f
  float* ddb    = (float*)(smem + 6144);     // 16 f
  float* h2b    = (float*)(smem + 6208);     // 512 f
  float* rb     = (float*)(smem + 8256);     // 32 f
  float* yb     = (float*)(smem + 8384);     // 32 f
  float* lgb    = (float*)(smem + 8512);     // 12 f
  float* rel2f  = (float*)(smem + 16384);
  float* brel2f = (float*)(smem + 20480);
  float* root2f = (float*)(smem + 20608);
  float* lin2f  = (float*)(smem + 24704);
  float* blin2f = (float*)(smem + 28800);
  float* lin3f  = (float*)(smem + 28928);
  float* blin3f = (float*)(smem + 30208);
  float* pbufH  = (float*)(smem + 40960);    // 512 f
  float* pbufL  = (float*)(smem + 43008);    // 512 f
  float* oadjH  = (float*)(smem + 45056);    // 256 f
  float* oadjL  = (float*)(smem + 46080);    // 256 f
  float* ssA    = (float*)(smem + 47104);    // 256 f
  float* ssB    = (float*)(smem + 48128);    // 256 f
  float* ssC    = (float*)(smem + 49152);    // 256 f

  const int n4 = t >> 2, q4 = t & 3;            // VALU stages
  const int wv = t >> 6, lane = t & 63;         // MFMA stages
  const int lm = lane & 15, quad = lane >> 4;
  const int mbase = wv * 16;

  // ---- P0: stage W1T bf16 hi/lo, biases, pool weights ----
  for (int e = t; e < 4096; e += 1024) {
    int k = e >> 5, c = e & 31;
    float w = ldf(P.wl1, e, BF);
    unsigned short hi = f2bf(w);
    w1th[c * 136 + k] = hi;
    w1tl[c * 136 + k] = f2bf(w - bf2f(hi));
  }
  if (t < 32) blin1f[t] = ldf(P.bl1, t, BF);
  if (t < 512) poolh[t] = f2bf(ldf(P.wp, t, BF));
  if (t < 16) bpoolf[t] = ldf(P.bp, t, BF);
  __syncthreads();

  // ---- P1: h0 = x @ W1 + b (MFMA; x from global, W hi/lo) ----
  {
    f32x4 acc[2] = {{0.f,0.f,0.f,0.f},{0.f,0.f,0.f,0.f}};
    const size_t node = (size_t)(b * 256 + mbase + lm);
    #pragma unroll
    for (int ks = 0; ks < 4; ++ks) {
      const int k0 = ks * 32 + quad * 8;
      s16x8 a;
      if (BF) {
        a = *(const s16x8*)((const unsigned short*)P.x + node * 128 + k0);
      } else {
        const float* xp = (const float*)P.x + node * 128 + k0;
        f32x4 v0 = *(const f32x4*)xp;
        f32x4 v1 = *(const f32x4*)(xp + 4);
        #pragma unroll
        for (int j = 0; j < 4; ++j) { a[j] = (short)f2bf(v0[j]); a[4 + j] = (short)f2bf(v1[j]); }
      }
      #pragma unroll
      for (int ct = 0; ct < 2; ++ct) {
        const int c = ct * 16 + lm;
        s16x8 bh = *(const s16x8*)(w1th + c * 136 + k0);
        s16x8 bl = *(const s16x8*)(w1tl + c * 136 + k0);
        acc[ct] = __builtin_amdgcn_mfma_f32_16x16x32_bf16(a, bh, acc[ct], 0, 0, 0);
        acc[ct] = __builtin_amdgcn_mfma_f32_16x16x32_bf16(a, bl, acc[ct], 0, 0, 0);
      }
    }
    #pragma unroll
    for (int ct = 0; ct < 2; ++ct) {
      const int c = ct * 16 + lm;
      float bias = blin1f[c];
      #pragma unroll
      for (int r = 0; r < 4; ++r) {
        int row = mbase + quad * 4 + r;
        float val = acc[ct][r] + bias;
        h0buf[row * 36 + c] = val;
        h0T[c * 264 + row] = f2bf(val);
      }
    }
  }
  __syncthreads();

  // ---- P2: zero adjacency region ----
  {
    uint4 z = {0u, 0u, 0u, 0u};
    for (int i = t; i < 4160; i += 1024) ((uint4*)smem)[i] = z;
  }
  __syncthreads();

  // ---- P3: build u8 adjacency ROW-major [u=src][v=dst], packed-byte atomics ----
  if (I64) {
    const long long* es = (const long long*)P.ei + (size_t)b * EPG;
    const long long* ed = (const long long*)P.ei + (size_t)NB * EPG + (size_t)b * EPG;
    #pragma unroll
    for (int i2 = 0; i2 < 8; ++i2) {
      int e = i2 * 1024 + t;
      unsigned idx = (unsigned)((((int)es[e]) & 255) * 260 + (((int)ed[e]) & 255));
      atomicAdd((unsigned int*)(smem + (idx & ~3u)), 1u << ((idx & 3u) * 8u));
    }
  } else {
    const int* es = (const int*)P.ei + (size_t)b * EPG;
    const int* ed = (const int*)P.ei + (size_t)NB * EPG + (size_t)b * EPG;
    #pragma unroll
    for (int i2 = 0; i2 < 8; ++i2) {
      int e = i2 * 1024 + t;
      unsigned idx = (unsigned)((es[e] & 255) * 260 + (ed[e] & 255));
      atomicAdd((unsigned int*)(smem + (idx & ~3u)), 1u << ((idx & 3u) * 8u));
    }
  }
  __syncthreads();

  // ---- P4: agg = A @ h0 (MFMA, A-frags cached; deg via shuffles) ----
  s16x8 afr[8];
  {
    f32x4 acc[2] = {{0.f,0.f,0.f,0.f},{0.f,0.f,0.f,0.f}};
    float dsum = 0.f;
    #pragma unroll
    for (int ks = 0; ks < 8; ++ks) {
      const int v0 = ks * 32 + quad * 8;
      const char* ap = smem + (mbase + lm) * 260 + v0;
      unsigned d0 = *(const unsigned int*)(ap);
      unsigned d1 = *(const unsigned int*)(ap + 4);
      s16x8 a;
      #pragma unroll
      for (int j = 0; j < 4; ++j) {
        float f0 = (float)((d0 >> (8 * j)) & 255u);
        float f1 = (float)((d1 >> (8 * j)) & 255u);
        dsum += f0 + f1;
        a[j] = ftrunc_bf(f0);
        a[4 + j] = ftrunc_bf(f1);
      }
      afr[ks] = a;
      #pragma unroll
      for (int ct = 0; ct < 2; ++ct) {
        s16x8 bf = *(const s16x8*)(h0T + (ct * 16 + lm) * 264 + v0);
        acc[ct] = __builtin_amdgcn_mfma_f32_16x16x32_bf16(a, bf, acc[ct], 0, 0, 0);
      }
    }
    #pragma unroll
    for (int ct = 0; ct < 2; ++ct) {
      const int c = ct * 16 + lm;
      #pragma unroll
      for (int r = 0; r < 4; ++r) aggbuf[(mbase + quad * 4 + r) * 36 + c] = acc[ct][r];
    }
    dsum += __shfl_xor(dsum, 16, 64);
    dsum += __shfl_xor(dsum, 32, 64);
    if (lane < 16) degb[mbase + lm] = dsum;
  }
  __syncthreads();

  // ---- stage conv1 weights transposed bf16 (over dead h0T) ----
  {
    int k = t >> 5, c = t & 31;
    float wr = ldf(P.wr1, t, BF);
    unsigned short hi = f2bf(wr);
    wrelTh[c * 40 + k] = hi;
    wrelTl[c * 40 + k] = f2bf(wr - bf2f(hi));
    wrootTh[c * 40 + k] = f2bf(ldf(P.wro1, t, BF));
  }
  if (t < 32) brel1f[t] = ldf(P.br1, t, BF);
  __syncthreads();

  // ---- Stage C: h1 = agg @ W_rel1 + b + h0 @ W_root1 (MFMA, 16-row tile/wave) ----
  f32x4 h1acc[2];
  float bias0, bias1;
  {
    s16x8 Ah, Al, Hh;
    const float* ar = aggbuf + (mbase + lm) * 36 + quad * 8;
    const float* hr = h0buf + (mbase + lm) * 36 + quad * 8;
    #pragma unroll
    for (int j = 0; j < 8; ++j) {
      float f = ar[j];
      unsigned short hi = f2bf(f);
      Ah[j] = (short)hi;
      Al[j] = (short)f2bf(f - bf2f(hi));
      Hh[j] = (short)f2bf(hr[j]);
    }
    bias0 = brel1f[lm]; bias1 = brel1f[16 + lm];
    #pragma unroll
    for (int ct = 0; ct < 2; ++ct) {
      const int c = ct * 16 + lm;
      s16x8 brh = *(const s16x8*)(wrelTh + c * 40 + quad * 8);
      s16x8 brl = *(const s16x8*)(wrelTl + c * 40 + quad * 8);
      s16x8 bwh = *(const s16x8*)(wrootTh + c * 40 + quad * 8);
      f32x4 acc = {0.f, 0.f, 0.f, 0.f};
      acc = __builtin_amdgcn_mfma_f32_16x16x32_bf16(Ah, brh, acc, 0, 0, 0);
      acc = __builtin_amdgcn_mfma_f32_16x16x32_bf16(Ah, brl, acc, 0, 0, 0);
      acc = __builtin_amdgcn_mfma_f32_16x16x32_bf16(Al, brh, acc, 0, 0, 0);
      acc = __builtin_amdgcn_mfma_f32_16x16x32_bf16(Hh, bwh, acc, 0, 0, 0);
      h1acc[ct] = acc;
    }
  }
  __syncthreads();   // all weight reads done; R3 -> h1Th; h0 dead
  {
    #pragma unroll
    for (int ct = 0; ct < 2; ++ct) {
      const int c = ct * 16 + lm;
      float bias = ct ? bias1 : bias0;
      #pragma unroll
      for (int r = 0; r < 4; ++r) {
        int row = mbase + quad * 4 + r;
        float val = h1acc[ct][r] + bias;
        aggbuf[row * 36 + c] = val;          // h1 f32 (Stage D reads rows)
        h1Th[c * 264 + row] = f2bf(val);     // h1T bf16 (P6 B-frags)
      }
    }
  }
  __syncthreads();

  // ---- Stage D: s = softmax(h1 @ W_pool + b); write sT bf16 hi/lo ----
  float ssq;
  {
    f32x4 sv = *(const f32x4*)(bpoolf + q4 * 4);
    const float* hrow = aggbuf + n4 * 36;
    #pragma unroll 8
    for (int m = 0; m < 32; ++m) {
      float hm = hrow[m];
      uint2 pw = *(const uint2*)(poolh + m * 16 + q4 * 4);
      sv[0] += hm * bf2f((unsigned short)(pw.x & 0xFFFFu));
      sv[1] += hm * bf2f((unsigned short)(pw.x >> 16));
      sv[2] += hm * bf2f((unsigned short)(pw.y & 0xFFFFu));
      sv[3] += hm * bf2f((unsigned short)(pw.y >> 16));
    }
    float mx = fmaxf(fmaxf(sv[0], sv[1]), fmaxf(sv[2], sv[3]));
    mx = fmaxf(mx, __shfl_xor(mx, 1, 64));
    mx = fmaxf(mx, __shfl_xor(mx, 2, 64));
    #pragma unroll
    for (int i = 0; i < 4; ++i) sv[i] = __expf(sv[i] - mx);
    float sm = sv[0] + sv[1] + sv[2] + sv[3];
    sm += __shfl_xor(sm, 1, 64);
    sm += __shfl_xor(sm, 2, 64);
    float inv = 1.f / sm;
    #pragma unroll
    for (int i = 0; i < 4; ++i) sv[i] *= inv;
    float sq = sv[0] * sv[0] + sv[1] * sv[1] + sv[2] * sv[2] + sv[3] * sv[3];
    sq += __shfl_xor(sq, 1, 64);
    sq += __shfl_xor(sq, 2, 64);
    ssq = sq;
    #pragma unroll
    for (int i = 0; i < 4; ++i) {
      int cl = q4 * 4 + i;
      unsigned short hi = f2bf(sv[i]);
      sTh[cl * 264 + n4] = hi;
      sTl[cl * 264 + n4] = f2bf(sv[i] - bf2f(hi));
    }
  }
  __syncthreads();

  // ---- P5: tA = A @ s (MFMA, cached A-frags, s hi/lo); write taT bf16 ----
  {
    f32x4 tacc = {0.f, 0.f, 0.f, 0.f};
    #pragma unroll
    for (int ks = 0; ks < 8; ++ks) {
      const int v0 = ks * 32 + quad * 8;
      s16x8 bh = *(const s16x8*)(sTh + lm * 264 + v0);
      s16x8 bl = *(const s16x8*)(sTl + lm * 264 + v0);
      tacc = __builtin_amdgcn_mfma_f32_16x16x32_bf16(afr[ks], bh, tacc, 0, 0, 0);
      tacc = __builtin_amdgcn_mfma_f32_16x16x32_bf16(afr[ks], bl, tacc, 0, 0, 0);
    }
    #pragma unroll
    for (int r = 0; r < 4; ++r) taT[lm * 264 + mbase + quad * 4 + r] = f2bf(tacc[r]);
  }
  __syncthreads();   // adjacency dead from here

  // ---- P6: FG weights into R0 + 9 MFMA reduction jobs on waves 0-8 ----
  rel2f[t] = ldf(P.wr2, t, BF);
  if (t < 32) brel2f[t] = ldf(P.br2, t, BF);
  root2f[t] = ldf(P.wro2, t, BF);
  lin2f[t] = ldf(P.wl2, t, BF);
  if (t < 32) blin2f[t] = ldf(P.bl2, t, BF);
  if (t < 320) lin3f[t] = ldf(P.wl3, t, BF);
  if (t < 10) blin3f[t] = ldf(P.bl3, t, BF);

  if (wv < 9) {
    const unsigned short *Ap, *Bp; float* dst; int W, ct = 0;
    switch (wv) {
      case 0: Ap = sTh; Bp = h1Th; dst = pbufH; W = 32; ct = 0; break;
      case 1: Ap = sTh; Bp = h1Th; dst = pbufH; W = 32; ct = 1; break;
      case 2: Ap = sTl; Bp = h1Th; dst = pbufL; W = 32; ct = 0; break;
      case 3: Ap = sTl; Bp = h1Th; dst = pbufL; W = 32; ct = 1; break;
      case 4: Ap = sTh; Bp = taT;  dst = oadjH; W = 16; break;
      case 5: Ap = sTl; Bp = taT;  dst = oadjL; W = 16; break;
      case 6: Ap = sTh; Bp = sTh;  dst = ssA;   W = 16; break;
      case 7: Ap = sTh; Bp = sTl;  dst = ssB;   W = 16; break;
      default: Ap = sTl; Bp = sTh; dst = ssC;   W = 16; break;
    }
    const int cidx = ct * 16 + lm;
    const unsigned short* Bb = Bp + cidx * 264;
    f32x4 acc = {0.f, 0.f, 0.f, 0.f};
    #pragma unroll
    for (int ch = 0; ch < 8; ++ch) {
      s16x8 a = *(const s16x8*)(Ap + lm * 264 + ch * 32 + quad * 8);
      s16x8 bb = *(const s16x8*)(Bb + ch * 32 + quad * 8);
      acc = __builtin_amdgcn_mfma_f32_16x16x32_bf16(a, bb, acc, 0, 0, 0);
    }
    #pragma unroll
    for (int r = 0; r < 4; ++r) dst[(quad * 4 + r) * W + cidx] = acc[r];
  }
  __syncthreads();

  // ---- combine job outputs ----
  if (t < 512) {
    pbuf[t] = pbufH[t] + pbufL[t];
  } else if (t < 768) {
    int i = t - 512; oadjb[i] = oadjH[i] + oadjL[i];
  } else {
    int i = t - 768; ssb[i] = ssA[i] + ssB[i] + ssC[i];
  }
  __syncthreads();

  // ---- losses ----
  {
    float den = block_sum16((q4 == 0) ? degb[n4] * ssq : 0.f, scr, t);
    float num = block_sum16((t < 16) ? oadjb[t * 17] : 0.f, scr, t);
    float fro = block_sum16((t < 256) ? ssb[t] * ssb[t] : 0.f, scr, t);
    float ssn = sqrtf(fro);
    float term = 0.f;
    if (t < 256) {
      float diag = ((t & 15) == (t >> 4)) ? 0.25f : 0.f;
      term = ssb[t] / ssn - diag;
    }
    float orth = block_sum16(term * term, scr, t);
    if (t == 0) {
      atomicAdd(P.ws, -(num / den) * (1.f / NB));
      atomicAdd(P.ws + 1, sqrtf(orth) * (1.f / NB));
    }
  }
  __syncthreads();

  // ---- P7: normalize pooled adjacency ----
  if (t < 16) {
    float rs = 0.f;
    #pragma unroll
    for (int j = 0; j < 16; ++j) if (j != t) rs += oadjb[t * 16 + j];
    ddb[t] = sqrtf(rs) + 1e-15f;
  }
  __syncthreads();
  if (t < 256) {
    int k = t >> 4, j = t & 15;
    float apv = (k == j) ? 0.f : oadjb[t] / (ddb[k] * ddb[j]);
    oadjb[t] = apv;
  }
  __syncthreads();

  // ---- conv2 + readout + MLP + log_softmax ----
  if (t < 512) {
    int k = t >> 5, c = t & 31;
    float q = 0.f;
    #pragma unroll
    for (int j = 0; j < 16; ++j) q += oadjb[k * 16 + j] * pbuf[j * 32 + c];
    qbuf[k * 32 + c] = q;
  }
  __syncthreads();
  if (t < 512) {
    int k = t >> 5, c = t & 31;
    float a1 = brel2f[c];
    #pragma unroll
    for (int m = 0; m < 32; ++m)
      a1 += qbuf[k * 32 + m] * rel2f[m * 32 + c] + pbuf[k * 32 + m] * root2f[m * 32 + c];
    h2b[k * 32 + c] = a1;
  }
  __syncthreads();
  if (t < 32) {
    float r = 0.f;
    #pragma unroll
    for (int k = 0; k < 16; ++k) r += h2b[k * 32 + t];
    rb[t] = r;
  }
  __syncthreads();
  if (t < 32) {
    float y = blin2f[t];
    #pragma unroll
    for (int m = 0; m < 32; ++m) y += rb[m] * lin2f[m * 32 + t];
    yb[t] = fmaxf(y, 0.f);
  }
  __syncthreads();
  if (t < 10) {
    float lg = blin3f[t];
    #pragma unroll
    for (int m = 0; m < 32; ++m) lg += yb[m] * lin3f[m * 10 + t];
    lgb[t] = lg;
  }
  __syncthreads();
  if (t == 0) {
    float mx = lgb[0];
    #pragma unroll
    for (int i = 1; i < 10; ++i) mx = fmaxf(mx, lgb[i]);
    float sum = 0.f;
    #pragma unroll
    for (int i = 0; i < 10; ++i) sum += __expf(lgb[i] - mx);
    lgb[10] = mx + __logf(sum);
  }
  __syncthreads();
  if (t < 10) {
    float val = lgb[t] - lgb[10];
    if (BF) ((unsigned short*)P.out)[b * 10 + t] = f2bf(val);
    else    P.out[b * 10 + t] = val;
  }
}

__global__ void mincut_fin(Params P) {
  if (threadIdx.x == 0) {
    const bool BF = detect_bf16(P.wr1);
    if (BF) {
      ((unsigned short*)P.out)[5120] = f2bf(P.ws[0]);
      ((unsigned short*)P.out)[5121] = f2bf(P.ws[1]);
    } else {
      P.out[5120] = P.ws[0];
      P.out[5121] = P.ws[1];
    }
  }
}

extern "C" void kernel_launch(void* const* d_in, const int* in_sizes, int n_in,
                              void* d_out, int out_size, void* d_ws, size_t ws_size,
                              hipStream_t stream) {
  (void)in_sizes; (void)n_in; (void)out_size; (void)ws_size;
  Params P;
  P.x    = d_in[0];
  P.ei   = d_in[1];
  P.wl1  = d_in[3];
  P.bl1  = d_in[4];
  P.wr1  = d_in[5];
  P.br1  = d_in[6];
  P.wro1 = d_in[7];
  P.wp   = d_in[8];
  P.bp   = d_in[9];
  P.wr2  = d_in[10];
  P.br2  = d_in[11];
  P.wro2 = d_in[12];
  P.wl2  = d_in[13];
  P.bl2  = d_in[14];
  P.wl3  = d_in[15];
  P.bl3  = d_in[16];
  P.out  = (float*)d_out;
  P.ws   = (float*)d_ws;

  hipMemsetAsync(d_ws, 0, 2 * sizeof(float), stream);
  hipFuncSetAttribute(reinterpret_cast<const void*>(mincut_main),
                      hipFuncAttributeMaxDynamicSharedMemorySize, SMEM_TOTAL);
  hipLaunchKernelGGL(mincut_main, dim3(NB), dim3(1024), SMEM_TOTAL, stream, P);
  hipLaunchKernelGGL(mincut_fin, dim3(1), dim3(64), 0, stream, P);
}

// Round 7
// 182.589 us; speedup vs baseline: 6.8702x; 1.0764x over previous
//
#include <hip/hip_runtime.h>

#define NB 512
#define NN 256
#define EPG 8192
#define FINC 128

typedef float f32x4 __attribute__((ext_vector_type(4)));
typedef short s16x8 __attribute__((ext_vector_type(8)));

__device__ __forceinline__ float bf2f(unsigned short u) {
  union { unsigned int i; float f; } x; x.i = ((unsigned int)u) << 16; return x.f;
}
__device__ __forceinline__ unsigned short f2bf(float f) {
  union { float f; unsigned int i; } x; x.f = f;
  unsigned int r = x.i + 0x7fffu + ((x.i >> 16) & 1u);
  return (unsigned short)(r >> 16);
}
// exact for small non-negative integers (counts <= 255)
__device__ __forceinline__ short ftrunc_bf(float f) {
  union { float f; unsigned int i; } x; x.f = f;
  return (short)(x.i >> 16);
}

struct Params {
  const void* x; const void* ei;
  const void *wl1, *bl1, *wr1, *br1, *wro1, *wp, *bp;
  const void *wr2, *br2, *wro2, *wl2, *bl2, *wl3, *bl3;
  float* out; float* ws;
};

// dtype probes (block-uniform); see round-1 notes.
__device__ __forceinline__ bool detect_bf16(const void* p) {
  const unsigned short* pw = (const unsigned short*)p;
  int sane = 0;
  for (int i = 0; i < 64; ++i) {
    unsigned e = (pw[i] >> 7) & 0xFFu;
    sane += (e > 96u && e < 132u) ? 1 : 0;
  }
  return sane >= 56;
}
__device__ __forceinline__ bool detect_i64(const void* p) {
  const int* pi = (const int*)p + EPG;
  int ok = 0;
  for (int i = 0; i < 32; ++i) ok += (pi[i] >= 256 && pi[i] < 512) ? 1 : 0;
  return ok < 24;
}
__device__ __forceinline__ float ldf(const void* p, int i, bool bf) {
  return bf ? bf2f(((const unsigned short*)p)[i]) : ((const float*)p)[i];
}

// ---- dynamic LDS layout (bytes) ----
// ADJ [0,67584):       adj u8 row-major [u][v] stride 264 (P0 zero..P5) ->
//                      tail buffers + FG weights + job outputs (P6 on)
// R1 [67584,104448):   h0 f32 stride 36 (P1->StageC); then taT@67584,
//                      sTh@76032, sTl@84480 (each [16][264] bf16)
// R2 [104448,141312):  W1T bf16 hi/lo [32][136] (P0->P1); then agg/h1 f32
//                      stride 36 (P4->StageD)
// R3 [141312,158208):  h0T bf16 [32][264] (P1->P4); then wrelTh/l+wrootTh
//                      [32][40]+brel1 (StageC); then h1Th bf16 (->P6)
// R4 [158208,162752):  poolTh/poolTl(2048) bpoolf(64) blin1f(128) scr(256)
//                      degb(1024) ssqb(1024)
#define SMEM_TOTAL 162752

__global__ __launch_bounds__(1024, 4) void mincut_main(Params P) {
  extern __shared__ char smem[];
  const int t = threadIdx.x;
  const int b = blockIdx.x;

  const bool BF  = detect_bf16(P.wr1);
  const bool I64 = detect_i64(P.ei);

  float* h0buf  = (float*)(smem + 67584);                    // stride 36
  unsigned short* taT = (unsigned short*)(smem + 67584);           // [16][264]
  unsigned short* sTh = (unsigned short*)(smem + 76032);           // [16][264]
  unsigned short* sTl = (unsigned short*)(smem + 84480);           // [16][264]
  float* aggbuf = (float*)(smem + 104448);                   // agg then h1, stride 36
  unsigned short* w1th = (unsigned short*)(smem + 104448);         // [32][136]
  unsigned short* w1tl = (unsigned short*)(smem + 113152);         // [32][136]
  unsigned short* h0T  = (unsigned short*)(smem + 141312);         // [32][264]
  unsigned short* wrelTh  = (unsigned short*)(smem + 141312);      // [32][40]
  unsigned short* wrelTl  = (unsigned short*)(smem + 143872);
  unsigned short* wrootTh = (unsigned short*)(smem + 146432);
  float* brel1f = (float*)(smem + 148992);                   // 32 f
  unsigned short* h1Th = (unsigned short*)(smem + 141312);         // [32][264] post-StageC
  unsigned short* poolTh = (unsigned short*)(smem + 158208);  // [16][32]
  unsigned short* poolTl = (unsigned short*)(smem + 159232);  // [16][32]
  float* bpoolf = (float*)(smem + 160256);                   // 16 f
  float* blin1f = (float*)(smem + 160320);                   // 32 f
  float* scr    = (float*)(smem + 160448);                   // 64 f
  float* degb   = (float*)(smem + 160704);                   // 256 f
  float* ssqb   = (float*)(smem + 161728);                   // 256 f
  // ADJ tail (valid from P6)
  float* pbuf   = (float*)(smem);            // 512 f
  float* oadjb  = (float*)(smem + 2048);     // 256 f
  float* ssb    = (float*)(smem + 3072);     // 256 f
  float* qbuf   = (float*)(smem + 4096);     // 512 f
  float* ddb    = (float*)(smem + 6144);     // 16 f
  float* h2b    = (float*)(smem + 6208);     // 512 f
  float* rb     = (float*)(smem + 8256);     // 32 f
  float* yb     = (float*)(smem + 8384);     // 32 f
  float* lgb    = (float*)(smem + 8512);     // 12 f
  float* rel2f  = (float*)(smem + 16384);
  float* root2f = (float*)(smem + 20608);
  float* lin2f  = (float*)(smem + 24704);
  float* lin3f  = (float*)(smem + 28928);
  float* pbufH  = (float*)(smem + 40960);    // 512 f
  float* pbufL  = (float*)(smem + 43008);    // 512 f
  float* oadjH  = (float*)(smem + 45056);    // 256 f
  float* oadjL  = (float*)(smem + 46080);    // 256 f
  float* ssA    = (float*)(smem + 47104);    // 256 f
  float* ssB    = (float*)(smem + 48128);    // 256 f
  float* ssC    = (float*)(smem + 49152);    // 256 f

  const int wv = t >> 6, lane = t & 63;
  const int lm = lane & 15, quad = lane >> 4;
  const int mbase = wv * 16;

  // ---- register prefetch: all small weights + edges (latency hides under P0/P1) ----
  float wrel_v  = ldf(P.wr1, t, BF);
  float wroot_v = ldf(P.wro1, t, BF);
  float brel1_v = (t < 32) ? ldf(P.br1, t, BF) : 0.f;
  float rel2_v  = ldf(P.wr2, t, BF);
  float root2_v = ldf(P.wro2, t, BF);
  float lin2_v  = ldf(P.wl2, t, BF);
  float lin3_v  = (t < 320) ? ldf(P.wl3, t, BF) : 0.f;
  float brel2_v = (t < 32) ? ldf(P.br2, t, BF) : 0.f;
  float blin2_v = (t < 32) ? ldf(P.bl2, t, BF) : 0.f;
  float blin3_v = (t < 10) ? ldf(P.bl3, t, BF) : 0.f;
  int eu[8], ev[8];
  if (I64) {
    const uint4* s4 = (const uint4*)((const long long*)P.ei + (size_t)b * EPG) + t * 4;
    const uint4* d4 = (const uint4*)((const long long*)P.ei + (size_t)NB * EPG + (size_t)b * EPG) + t * 4;
    #pragma unroll
    for (int i = 0; i < 4; ++i) {
      uint4 a = s4[i], c = d4[i];
      eu[2 * i] = a.x & 255; eu[2 * i + 1] = a.z & 255;
      ev[2 * i] = c.x & 255; ev[2 * i + 1] = c.z & 255;
    }
  } else {
    const uint4* s4 = (const uint4*)((const int*)P.ei + (size_t)b * EPG) + t * 2;
    const uint4* d4 = (const uint4*)((const int*)P.ei + (size_t)NB * EPG + (size_t)b * EPG) + t * 2;
    #pragma unroll
    for (int i = 0; i < 2; ++i) {
      uint4 a = s4[i], c = d4[i];
      eu[4 * i] = a.x & 255; eu[4 * i + 1] = a.y & 255; eu[4 * i + 2] = a.z & 255; eu[4 * i + 3] = a.w & 255;
      ev[4 * i] = c.x & 255; ev[4 * i + 1] = c.y & 255; ev[4 * i + 2] = c.z & 255; ev[4 * i + 3] = c.w & 255;
    }
  }

  // ---- P0: zero adjacency + stage W1T hi/lo, WpoolT hi/lo, biases ----
  {
    uint4 z = {0u, 0u, 0u, 0u};
    for (int i = t; i < 4224; i += 1024) ((uint4*)smem)[i] = z;
  }
  for (int e = t; e < 4096; e += 1024) {
    int k = e >> 5, c = e & 31;
    float w = ldf(P.wl1, e, BF);
    unsigned short hi = f2bf(w);
    w1th[c * 136 + k] = hi;
    w1tl[c * 136 + k] = f2bf(w - bf2f(hi));
  }
  if (t < 512) {
    int m = t >> 4, c = t & 15;
    float w = ldf(P.wp, t, BF);
    unsigned short hi = f2bf(w);
    poolTh[c * 32 + m] = hi;
    poolTl[c * 32 + m] = f2bf(w - bf2f(hi));
  }
  if (t < 32) blin1f[t] = ldf(P.bl1, t, BF);
  if (t < 16) bpoolf[t] = ldf(P.bp, t, BF);
  __syncthreads();   // B1

  // ---- P3: adjacency atomics (fire-and-forget) ----
  #pragma unroll
  for (int e = 0; e < 8; ++e) {
    unsigned idx = (unsigned)(eu[e] * 264 + ev[e]);
    atomicAdd((unsigned int*)(smem + (idx & ~3u)), 1u << ((idx & 3u) * 8u));
  }

  // ---- P1: h0 = x @ W1 + b (MFMA; x from global, W hi/lo) ----
  {
    f32x4 acc[2] = {{0.f,0.f,0.f,0.f},{0.f,0.f,0.f,0.f}};
    const size_t node = (size_t)(b * 256 + mbase + lm);
    #pragma unroll
    for (int ks = 0; ks < 4; ++ks) {
      const int k0 = ks * 32 + quad * 8;
      s16x8 a;
      if (BF) {
        a = *(const s16x8*)((const unsigned short*)P.x + node * 128 + k0);
      } else {
        const float* xp = (const float*)P.x + node * 128 + k0;
        f32x4 v0 = *(const f32x4*)xp;
        f32x4 v1 = *(const f32x4*)(xp + 4);
        #pragma unroll
        for (int j = 0; j < 4; ++j) { a[j] = (short)f2bf(v0[j]); a[4 + j] = (short)f2bf(v1[j]); }
      }
      #pragma unroll
      for (int ct = 0; ct < 2; ++ct) {
        const int c = ct * 16 + lm;
        s16x8 bh = *(const s16x8*)(w1th + c * 136 + k0);
        s16x8 bl = *(const s16x8*)(w1tl + c * 136 + k0);
        acc[ct] = __builtin_amdgcn_mfma_f32_16x16x32_bf16(a, bh, acc[ct], 0, 0, 0);
        acc[ct] = __builtin_amdgcn_mfma_f32_16x16x32_bf16(a, bl, acc[ct], 0, 0, 0);
      }
    }
    #pragma unroll
    for (int ct = 0; ct < 2; ++ct) {
      const int c = ct * 16 + lm;
      float bias = blin1f[c];
      #pragma unroll
      for (int r = 0; r < 4; ++r) {
        int row = mbase + quad * 4 + r;
        float val = acc[ct][r] + bias;
        h0buf[row * 36 + c] = val;
        h0T[c * 264 + row] = f2bf(val);
      }
    }
  }
  __syncthreads();   // B2: adjacency + h0 ready

  // ---- P4: agg = A @ h0 (MFMA, A-frags cached; deg via shuffles) ----
  s16x8 afr[8];
  {
    f32x4 acc[2] = {{0.f,0.f,0.f,0.f},{0.f,0.f,0.f,0.f}};
    float dsum = 0.f;
    const char* arow_ = smem + (mbase + lm) * 264;
    #pragma unroll
    for (int ks = 0; ks < 8; ++ks) {
      const int v0 = ks * 32 + quad * 8;
      uint2 d = *(const uint2*)(arow_ + v0);
      s16x8 a;
      #pragma unroll
      for (int j = 0; j < 4; ++j) {
        float f0 = (float)((d.x >> (8 * j)) & 255u);
        float f1 = (float)((d.y >> (8 * j)) & 255u);
        dsum += f0 + f1;
        a[j] = ftrunc_bf(f0);
        a[4 + j] = ftrunc_bf(f1);
      }
      afr[ks] = a;
      #pragma unroll
      for (int ct = 0; ct < 2; ++ct) {
        s16x8 bf = *(const s16x8*)(h0T + (ct * 16 + lm) * 264 + v0);
        acc[ct] = __builtin_amdgcn_mfma_f32_16x16x32_bf16(a, bf, acc[ct], 0, 0, 0);
      }
    }
    #pragma unroll
    for (int ct = 0; ct < 2; ++ct) {
      const int c = ct * 16 + lm;
      #pragma unroll
      for (int r = 0; r < 4; ++r) aggbuf[(mbase + quad * 4 + r) * 36 + c] = acc[ct][r];
    }
    dsum += __shfl_xor(dsum, 16, 64);
    dsum += __shfl_xor(dsum, 32, 64);
    if (lane < 16) degb[mbase + lm] = dsum;
  }
  __syncthreads();   // B3: h0T dead

  // ---- Wc: conv1 weights from regs -> R3 ----
  {
    int k = t >> 5, c = t & 31;
    unsigned short hi = f2bf(wrel_v);
    wrelTh[c * 40 + k] = hi;
    wrelTl[c * 40 + k] = f2bf(wrel_v - bf2f(hi));
    wrootTh[c * 40 + k] = f2bf(wroot_v);
  }
  if (t < 32) brel1f[t] = brel1_v;
  __syncthreads();   // B4

  // ---- Stage C: h1 = agg @ W_rel1 + b + h0 @ W_root1 (MFMA, 16-row tile/wave) ----
  f32x4 h1acc[2];
  float bias0, bias1;
  {
    s16x8 Ah, Al, Hh;
    const float* ar = aggbuf + (mbase + lm) * 36 + quad * 8;
    const float* hr = h0buf + (mbase + lm) * 36 + quad * 8;
    #pragma unroll
    for (int j = 0; j < 8; ++j) {
      float f = ar[j];
      unsigned short hi = f2bf(f);
      Ah[j] = (short)hi;
      Al[j] = (short)f2bf(f - bf2f(hi));
      Hh[j] = (short)f2bf(hr[j]);
    }
    bias0 = brel1f[lm]; bias1 = brel1f[16 + lm];
    #pragma unroll
    for (int ct = 0; ct < 2; ++ct) {
      const int c = ct * 16 + lm;
      s16x8 brh = *(const s16x8*)(wrelTh + c * 40 + quad * 8);
      s16x8 brl = *(const s16x8*)(wrelTl + c * 40 + quad * 8);
      s16x8 bwh = *(const s16x8*)(wrootTh + c * 40 + quad * 8);
      f32x4 acc = {0.f, 0.f, 0.f, 0.f};
      acc = __builtin_amdgcn_mfma_f32_16x16x32_bf16(Ah, brh, acc, 0, 0, 0);
      acc = __builtin_amdgcn_mfma_f32_16x16x32_bf16(Ah, brl, acc, 0, 0, 0);
      acc = __builtin_amdgcn_mfma_f32_16x16x32_bf16(Al, brh, acc, 0, 0, 0);
      acc = __builtin_amdgcn_mfma_f32_16x16x32_bf16(Hh, bwh, acc, 0, 0, 0);
      h1acc[ct] = acc;
    }
  }
  __syncthreads();   // B5: weight/h0 reads done; R3 -> h1Th; h0buf dead
  {
    #pragma unroll
    for (int ct = 0; ct < 2; ++ct) {
      const int c = ct * 16 + lm;
      float bias = ct ? bias1 : bias0;
      #pragma unroll
      for (int r = 0; r < 4; ++r) {
        int row = mbase + quad * 4 + r;
        float val = h1acc[ct][r] + bias;
        aggbuf[row * 36 + c] = val;          // h1 f32 (Stage D A-frags, own tile)
        h1Th[c * 264 + row] = f2bf(val);     // h1T bf16 (P6 B-frags)
      }
    }
  }
  // ---- Stage D (no barrier: own-tile LDS round-trip, in-wave ordering) ----
  // logits = h1 @ Wpool + b (3 mfma, hi/lo), softmax across 16 lanes
  {
    s16x8 Ah, Al;
    const float* hr = aggbuf + (mbase + lm) * 36 + quad * 8;
    #pragma unroll
    for (int j = 0; j < 8; ++j) {
      float f = hr[j];
      unsigned short hi = f2bf(f);
      Ah[j] = (short)hi;
      Al[j] = (short)f2bf(f - bf2f(hi));
    }
    s16x8 Bh = *(const s16x8*)(poolTh + lm * 32 + quad * 8);
    s16x8 Bl = *(const s16x8*)(poolTl + lm * 32 + quad * 8);
    f32x4 lg = {0.f, 0.f, 0.f, 0.f};
    lg = __builtin_amdgcn_mfma_f32_16x16x32_bf16(Ah, Bh, lg, 0, 0, 0);
    lg = __builtin_amdgcn_mfma_f32_16x16x32_bf16(Al, Bh, lg, 0, 0, 0);
    lg = __builtin_amdgcn_mfma_f32_16x16x32_bf16(Ah, Bl, lg, 0, 0, 0);
    float bp = bpoolf[lm];
    #pragma unroll
    for (int r = 0; r < 4; ++r) lg[r] += bp;
    f32x4 mx = lg;
    #pragma unroll
    for (int m = 1; m <= 8; m <<= 1) {
      #pragma unroll
      for (int r = 0; r < 4; ++r) mx[r] = fmaxf(mx[r], __shfl_xor(mx[r], m, 64));
    }
    #pragma unroll
    for (int r = 0; r < 4; ++r) lg[r] = __expf(lg[r] - mx[r]);
    f32x4 sm = lg;
    #pragma unroll
    for (int m = 1; m <= 8; m <<= 1) {
      #pragma unroll
      for (int r = 0; r < 4; ++r) sm[r] += __shfl_xor(sm[r], m, 64);
    }
    f32x4 sq;
    #pragma unroll
    for (int r = 0; r < 4; ++r) {
      lg[r] = lg[r] / sm[r];
      sq[r] = lg[r] * lg[r];
    }
    #pragma unroll
    for (int m = 1; m <= 8; m <<= 1) {
      #pragma unroll
      for (int r = 0; r < 4; ++r) sq[r] += __shfl_xor(sq[r], m, 64);
    }
    #pragma unroll
    for (int r = 0; r < 4; ++r) {
      int node = mbase + quad * 4 + r;
      unsigned short hi = f2bf(lg[r]);
      sTh[lm * 264 + node] = hi;
      sTl[lm * 264 + node] = f2bf(lg[r] - bf2f(hi));
    }
    if (lm == 0) {
      #pragma unroll
      for (int r = 0; r < 4; ++r) ssqb[mbase + quad * 4 + r] = sq[r];
    }
  }
  __syncthreads();   // B6: s ready block-wide

  // ---- P5: tA = A @ s (MFMA, cached A-frags, s hi/lo); write taT bf16 ----
  {
    f32x4 tacc = {0.f, 0.f, 0.f, 0.f};
    #pragma unroll
    for (int ks = 0; ks < 8; ++ks) {
      const int v0 = ks * 32 + quad * 8;
      s16x8 bh = *(const s16x8*)(sTh + lm * 264 + v0);
      s16x8 bl = *(const s16x8*)(sTl + lm * 264 + v0);
      tacc = __builtin_amdgcn_mfma_f32_16x16x32_bf16(afr[ks], bh, tacc, 0, 0, 0);
      tacc = __builtin_amdgcn_mfma_f32_16x16x32_bf16(afr[ks], bl, tacc, 0, 0, 0);
    }
    #pragma unroll
    for (int r = 0; r < 4; ++r) taT[lm * 264 + mbase + quad * 4 + r] = f2bf(tacc[r]);
  }
  __syncthreads();   // B7: adjacency dead

  // ---- P6: FG weights from regs -> ADJ tail + 9 MFMA reduction jobs ----
  rel2f[t] = rel2_v;
  root2f[t] = root2_v;
  lin2f[t] = lin2_v;
  if (t < 320) lin3f[t] = lin3_v;

  if (wv < 9) {
    const unsigned short *Ap, *Bp; float* dst; int W, ct = 0;
    switch (wv) {
      case 0: Ap = sTh; Bp = h1Th; dst = pbufH; W = 32; ct = 0; break;
      case 1: Ap = sTh; Bp = h1Th; dst = pbufH; W = 32; ct = 1; break;
      case 2: Ap = sTl; Bp = h1Th; dst = pbufL; W = 32; ct = 0; break;
      case 3: Ap = sTl; Bp = h1Th; dst = pbufL; W = 32; ct = 1; break;
      case 4: Ap = sTh; Bp = taT;  dst = oadjH; W = 16; break;
      case 5: Ap = sTl; Bp = taT;  dst = oadjL; W = 16; break;
      case 6: Ap = sTh; Bp = sTh;  dst = ssA;   W = 16; break;
      case 7: Ap = sTh; Bp = sTl;  dst = ssB;   W = 16; break;
      default: Ap = sTl; Bp = sTh; dst = ssC;   W = 16; break;
    }
    const int cidx = ct * 16 + lm;
    const unsigned short* Bb = Bp + cidx * 264;
    f32x4 acc = {0.f, 0.f, 0.f, 0.f};
    #pragma unroll
    for (int ch = 0; ch < 8; ++ch) {
      s16x8 a = *(const s16x8*)(Ap + lm * 264 + ch * 32 + quad * 8);
      s16x8 bb = *(const s16x8*)(Bb + ch * 32 + quad * 8);
      acc = __builtin_amdgcn_mfma_f32_16x16x32_bf16(a, bb, acc, 0, 0, 0);
    }
    #pragma unroll
    for (int r = 0; r < 4; ++r) dst[(quad * 4 + r) * W + cidx] = acc[r];
  }
  __syncthreads();   // B8

  // ---- combine job outputs ----
  if (t < 512) {
    pbuf[t] = pbufH[t] + pbufL[t];
  } else if (t < 768) {
    int i = t - 512; oadjb[i] = oadjH[i] + oadjL[i];
  } else {
    int i = t - 768; ssb[i] = ssA[i] + ssB[i] + ssC[i];
  }
  __syncthreads();   // B9

  // ---- losses: single 4-value butterfly; orth via closed form ----
  {
    float vden = (t < 256) ? degb[t] * ssqb[t] : 0.f;
    float vnum = (t < 16) ? oadjb[t * 17] : 0.f;
    float vfro = (t < 256) ? ssb[t] * ssb[t] : 0.f;
    float vtr  = (t < 16) ? ssb[t * 17] : 0.f;
    #pragma unroll
    for (int o = 32; o > 0; o >>= 1) {
      vden += __shfl_xor(vden, o, 64);
      vnum += __shfl_xor(vnum, o, 64);
      vfro += __shfl_xor(vfro, o, 64);
      vtr  += __shfl_xor(vtr, o, 64);
    }
    if (lane == 0) { scr[wv] = vden; scr[16 + wv] = vnum; scr[32 + wv] = vfro; scr[48 + wv] = vtr; }
  }
  __syncthreads();   // B10
  if (t == 0) {
    float den = 0.f, num = 0.f, fro = 0.f, tr = 0.f;
    #pragma unroll
    for (int i = 0; i < 16; ++i) { den += scr[i]; num += scr[16 + i]; fro += scr[32 + i]; tr += scr[48 + i]; }
    float ssn = sqrtf(fro);
    float orth2 = 2.f - tr / (2.f * ssn);
    atomicAdd(P.ws, -(num / den) * (1.f / NB));
    atomicAdd(P.ws + 1, sqrtf(fmaxf(orth2, 0.f)) * (1.f / NB));
  }
  if (t < 16) {
    float rs = 0.f;
    #pragma unroll
    for (int j = 0; j < 16; ++j) if (j != t) rs += oadjb[t * 16 + j];
    ddb[t] = sqrtf(rs) + 1e-15f;
  }
  __syncthreads();   // B11
  if (t < 256) {
    int k = t >> 4, j = t & 15;
    float apv = (k == j) ? 0.f : oadjb[t] / (ddb[k] * ddb[j]);
    oadjb[t] = apv;
  }
  __syncthreads();   // B12

  // ---- conv2 ----
  if (t < 512) {
    int k = t >> 5, c = t & 31;
    float q = 0.f;
    #pragma unroll
    for (int j = 0; j < 16; ++j) q += oadjb[k * 16 + j] * pbuf[j * 32 + c];
    qbuf[k * 32 + c] = q;
  }
  __syncthreads();   // B13
  if (t < 512) {
    int k = t >> 5, c = t & 31;
    float a1 = brel2_v;
    a1 = ((float*)nullptr == nullptr) ? a1 : a1;  // keep reg
    float acc = (t < 32) ? 0.f : 0.f;
    (void)acc;
    float s0 = 0.f;
    #pragma unroll
    for (int m = 0; m < 32; ++m)
      s0 += qbuf[k * 32 + m] * rel2f[m * 32 + c] + pbuf[k * 32 + m] * root2f[m * 32 + c];
    // brel2 bias: brel2_v only valid on t<32; read staged value via shuffle-free LDS-less path:
    h2b[k * 32 + c] = s0;
  }
  __syncthreads();   // B14

  // ---- wave-0 tail: bias+readout+MLP+log_softmax, zero barriers ----
  if (wv == 0) {
    if (lane < 32) {
      float r = 32.f * brel2_v;   // bias added once per k across 16 k-rows: handled below
      r = 0.f;
      #pragma unroll
      for (int k = 0; k < 16; ++k) r += h2b[k * 32 + lane];
      r += 16.f * brel2_v;        // h2[k][c] lacked bias; add 16*b here (sum over k)
      rb[lane] = r;
    }
    if (lane < 32) {
      float y = blin2_v;
      #pragma unroll
      for (int m = 0; m < 32; ++m) y += rb[m] * lin2f[m * 32 + lane];
      yb[lane] = fmaxf(y, 0.f);
    }
    if (lane < 10) {
      float lg = blin3_v;
      #pragma unroll
      for (int m = 0; m < 32; ++m) lg += yb[m] * lin3f[m * 10 + lane];
      lgb[lane] = lg;
    }
    if (lane == 0) {
      float mx = lgb[0];
      #pragma unroll
      for (int i = 1; i < 10; ++i) mx = fmaxf(mx, lgb[i]);
      float sum = 0.f;
      #pragma unroll
      for (int i = 0; i < 10; ++i) sum += __expf(lgb[i] - mx);
      lgb[10] = mx + __logf(sum);
    }
    if (lane < 10) {
      float val = lgb[lane] - lgb[10];
      if (BF) ((unsigned short*)P.out)[b * 10 + lane] = f2bf(val);
      else    P.out[b * 10 + lane] = val;
    }
  }
}

__global__ void mincut_fin(Params P) {
  if (threadIdx.x == 0) {
    const bool BF = detect_bf16(P.wr1);
    if (BF) {
      ((unsigned short*)P.out)[5120] = f2bf(P.ws[0]);
      ((unsigned short*)P.out)[5121] = f2bf(P.ws[1]);
    } else {
      P.out[5120] = P.ws[0];
      P.out[5121] = P.ws[1];
    }
  }
}

extern "C" void kernel_launch(void* const* d_in, const int* in_sizes, int n_in,
                              void* d_out, int out_size, void* d_ws, size_t ws_size,
                              hipStream_t stream) {
  (void)in_sizes; (void)n_in; (void)out_size; (void)ws_size;
  Params P;
  P.x    = d_in[0];
  P.ei   = d_in[1];
  P.wl1  = d_in[3];
  P.bl1  = d_in[4];
  P.wr1  = d_in[5];
  P.br1  = d_in[6];
  P.wro1 = d_in[7];
  P.wp   = d_in[8];
  P.bp   = d_in[9];
  P.wr2  = d_in[10];
  P.br2  = d_in[11];
  P.wro2 = d_in[12];
  P.wl2  = d_in[13];
  P.bl2  = d_in[14];
  P.wl3  = d_in[15];
  P.bl3  = d_in[16];
  P.out  = (float*)d_out;
  P.ws   = (float*)d_ws;

  hipMemsetAsync(d_ws, 0, 2 * sizeof(float), stream);
  hipFuncSetAttribute(reinterpret_cast<const void*>(mincut_main),
                      hipFuncAttributeMaxDynamicSharedMemorySize, SMEM_TOTAL);
  hipLaunchKernelGGL(mincut_main, dim3(NB), dim3(1024), SMEM_TOTAL, stream, P);
  hipLaunchKernelGGL(mincut_fin, dim3(1), dim3(64), 0, stream, P);
}